// Round 15
// baseline (324.399 us; speedup 1.0000x reference)
//
#include <hip/hip_runtime.h>
#include <stdint.h>

#define E_N 8192
#define SPLIT 8
#define CH 16                 // (E_N/SPLIT)/64 kv-chunks per split
#define QBLK 128              // 8 waves x 16 q-rows

typedef unsigned short u16;
typedef unsigned int u32;
typedef unsigned long long u64;
typedef __attribute__((ext_vector_type(4))) float f32x4;
typedef __attribute__((ext_vector_type(8))) short bf16x8;
typedef __attribute__((ext_vector_type(4))) unsigned int u32x4;
typedef __attribute__((ext_vector_type(2))) unsigned int u32x2;

union V16 { u32x4 q; bf16x8 h; u16 u[8]; };

static __device__ __forceinline__ u16 f2bf(float f) {
  union { float f; unsigned u; } c; c.f = f;
  unsigned r = c.u + 0x7FFFu + ((c.u >> 16) & 1u);
  return (u16)(r >> 16);
}

// q pre-scale folds softmax 1/sqrt(128) and log2(e) so inner loop is exp2.
constexpr float QS = 1.4426950408889634f / 11.313708498984761f;

// ---------- kernel 0: W[256][128] f32 -> Wt bf16 [2][128][256]
__global__ void k_wt(const float* __restrict__ Wq, const float* __restrict__ Wk,
                     u16* __restrict__ wt) {
  int idx = blockIdx.x * 256 + threadIdx.x;          // 0..65535
  int mat = idx >> 15, rem = idx & 32767;
  float v = mat ? Wk[rem] : Wq[rem];
  int d = rem >> 7, c = rem & 127;
  wt[(mat * 128 + c) * 256 + d] = f2bf(v);
}

// ---------- kernel 1: projections q (scaled) and k, bf16 [8192][128]
__launch_bounds__(256)
__global__ void k_proj(const float* __restrict__ X, const u16* __restrict__ wt,
                       u16* __restrict__ qg, u16* __restrict__ kg) {
  __shared__ __align__(16) char Xs[64 * 512];        // bf16 [64][256], xor-swizzled
  const int tid = threadIdx.x;
  const int wid = tid >> 6, lane = tid & 63, g = lane >> 4, l15 = lane & 15;
  const int r0 = blockIdx.x * 64;
#pragma unroll
  for (int i = 0; i < 16; ++i) {
    int s = tid + 256 * i;                           // 0..4095 float4 tasks
    int row = s >> 6, c4 = (s & 63) << 2;
    f32x4 v = *(const f32x4*)(X + (size_t)(r0 + row) * 256 + c4);
    u32x2 pk;
    pk[0] = f2bf(v[0]) | ((unsigned)f2bf(v[1]) << 16);
    pk[1] = f2bf(v[2]) | ((unsigned)f2bf(v[3]) << 16);
    *(u32x2*)(Xs + (((row << 9) + (c4 << 1)) ^ ((row & 7) << 4))) = pk;
  }
  __syncthreads();
  bf16x8 xa[8];
  const int arow = wid * 16 + l15;
#pragma unroll
  for (int ks = 0; ks < 8; ++ks) {
    V16 t; t.q = *(const u32x4*)(Xs + (((arow << 9) + (ks << 6) + (g << 4)) ^ ((l15 & 7) << 4)));
    xa[ks] = t.h;
  }
  const f32x4 zero4 = {0.f, 0.f, 0.f, 0.f};
  f32x4 acc[16];
#pragma unroll
  for (int i = 0; i < 16; ++i) acc[i] = zero4;
#pragma unroll
  for (int ct = 0; ct < 16; ++ct) {
    int mat = ct >> 3, c = ((ct & 7) << 4) + l15;
#pragma unroll
    for (int ks = 0; ks < 8; ++ks) {
      V16 b; b.q = *(const u32x4*)(wt + ((mat * 128 + c) * 256 + (ks << 5) + (g << 3)));
      acc[ct] = __builtin_amdgcn_mfma_f32_16x16x32_bf16(xa[ks], b.h, acc[ct], 0, 0, 0);
    }
  }
#pragma unroll
  for (int ct = 0; ct < 16; ++ct) {
    int mat = ct >> 3, c = ((ct & 7) << 4) + l15;
#pragma unroll
    for (int r = 0; r < 4; ++r) {
      int row = r0 + wid * 16 + 4 * g + r;
      float v = acc[ct][r];
      if (mat == 0) qg[row * 128 + c] = f2bf(v * QS);
      else          kg[row * 128 + c] = f2bf(v);
    }
  }
}

// ---------- kernel 2: kt[128][8192] = k^T (bf16), LDS-tiled transpose
__global__ void k_kt(const u16* __restrict__ kg, u16* __restrict__ ktg) {
  __shared__ __align__(16) u16 Ts[64 * 66];          // pitch 66 (132 B) for bank spread
  const int tid = threadIdx.x;
  const int b = blockIdx.x;
  const int r0 = (b >> 1) * 64, c0 = (b & 1) * 64;
#pragma unroll
  for (int i = 0; i < 2; ++i) {
    int s = tid + 256 * i;                           // 0..511
    int row = s >> 3, seg = s & 7;
    u32x4 v = *(const u32x4*)(kg + (size_t)(r0 + row) * 128 + c0 + seg * 8);
    unsigned* dst = (unsigned*)((char*)Ts + row * 132 + seg * 16);
    dst[0] = v[0]; dst[1] = v[1]; dst[2] = v[2]; dst[3] = v[3];
  }
  __syncthreads();
#pragma unroll
  for (int i = 0; i < 2; ++i) {
    int s = tid + 256 * i;
    int oc = s >> 3, seg2 = s & 7;
    u16 t[8];
#pragma unroll
    for (int j = 0; j < 8; ++j) t[j] = Ts[(seg2 * 8 + j) * 66 + oc];
    u32x4 o;
    o[0] = t[0] | ((unsigned)t[1] << 16);
    o[1] = t[2] | ((unsigned)t[3] << 16);
    o[2] = t[4] | ((unsigned)t[5] << 16);
    o[3] = t[6] | ((unsigned)t[7] << 16);
    *(u32x4*)(ktg + (size_t)(c0 + oc) * E_N + r0 + seg2 * 8) = o;
  }
}

// lgkm-only barrier: raw s_barrier WITHOUT the vmcnt(0) drain (T3/T4) ->
// global loads stay in flight across step boundaries.
#define BARRIER() { asm volatile("s_waitcnt lgkmcnt(0)" ::: "memory"); \
                    __builtin_amdgcn_s_barrier(); }

// Reg-staged tile load, 512-thread split: 4 x global dwordx4 per thread.
#define LOADREGS(KV1)                                                           \
  {                                                                             \
    const u16* kp = kgp + (size_t)(KV1) * 128;                                  \
    kr0 = *(const u32x4*)(kp);                                                  \
    kr1 = *(const u32x4*)(kp + 64);                                             \
    const u16* tp = ktp + (KV1);                                                \
    tr0 = *(const u32x4*)(tp);                                                  \
    tr1 = *(const u32x4*)(tp + 32);                                             \
  }

#define WRITELDS(KW, TW)                                                        \
  {                                                                             \
    *(u32x4*)((KW) + kofs0) = kr0;                                              \
    *(u32x4*)((KW) + kofs1) = kr1;                                              \
    *(u32x4*)((TW) + tofs0) = tr0;                                              \
    *(u32x4*)((TW) + tofs1) = tr1;                                              \
  }

// Mask: lane (g,l15) reads M[qrow=l15][kv0+16t+4g..+3] as one dwordx4 per t
// (swapped-QK^T layout: S^T col=qrow=l15, row=kv=16t+4g+r).
#define MASKLOAD(KV1)                                                           \
  {                                                                             \
    _Pragma("unroll")                                                           \
    for (int t4 = 0; t4 < 4; ++t4)                                              \
      mq[t4] = *(const u32x4*)(mrow + (KV1) + t4 * 16);                         \
  }

// Compress 16 mask ints -> 16-bit field (bit 4t+c <-> kv=16t+4g+c); frees the
// 16-register load set before the next step's peak pressure.
#define COMPRESS() ({                                                           \
    u32 _m = 0;                                                                 \
    _Pragma("unroll")                                                           \
    for (int t = 0; t < 4; ++t) {                                               \
      _Pragma("unroll")                                                         \
      for (int c = 0; c < 4; ++c)                                               \
        _m |= (mq[t][c] != 0) ? (1u << (4 * t + c)) : 0u;                       \
    }                                                                           \
    _m; })

// One flash step, ONE lgkm-barrier. Reads KR/TR (chunk st), writes KW/TW
// (chunk st+1, regs staged last step), issues chunk st+2 loads + chunk st+1
// masks; compresses masks at step end (full-step vmem slack).
#define FSTEP(ST, KR, TR, KW, TW, DOM, DOW, DOP)                                \
  {                                                                             \
    if (DOM) MASKLOAD(kvbase + ((((ST) + 1 + qb) & 15) << 6))                   \
    f32x4 S[4];                                                                 \
    _Pragma("unroll")                                                           \
    for (int t = 0; t < 4; ++t) S[t] = zero4;                                   \
    _Pragma("unroll")                                                           \
    for (int t = 0; t < 4; ++t) {                                               \
      int krow = t * 16 + l15;                                                  \
      _Pragma("unroll")                                                         \
      for (int ks = 0; ks < 4; ++ks) {                                          \
        V16 kf; kf.q = *(const u32x4*)((KR) + (((krow << 8) + (ks << 6) + (g << 4)) ^ ((l15 & 7) << 4))); \
        S[t] = __builtin_amdgcn_mfma_f32_16x16x32_bf16(kf.h, qf[ks], S[t], 0, 0, 0); \
      }                                                                         \
    }                                                                           \
    _Pragma("unroll")                                                           \
    for (int t = 0; t < 4; ++t) {                                               \
      float p0 = ((mbcur >> (4 * t + 0)) & 1u) ? __builtin_amdgcn_exp2f(S[t][0]) : 0.f; \
      float p1 = ((mbcur >> (4 * t + 1)) & 1u) ? __builtin_amdgcn_exp2f(S[t][1]) : 0.f; \
      float p2 = ((mbcur >> (4 * t + 2)) & 1u) ? __builtin_amdgcn_exp2f(S[t][2]) : 0.f; \
      float p3 = ((mbcur >> (4 * t + 3)) & 1u) ? __builtin_amdgcn_exp2f(S[t][3]) : 0.f; \
      lacc += (p0 + p1) + (p2 + p3);                                            \
      u32x2 pk;                                                                 \
      pk[0] = f2bf(p0) | ((u32)f2bf(p1) << 16);                                 \
      pk[1] = f2bf(p2) | ((u32)f2bf(p3) << 16);                                 \
      *(u32x2*)(Pw + ((l15 * 128 + (t * 16 + 4 * g) * 2) ^ ((l15 & 7) << 4))) = pk; \
    }                                                                           \
    bf16x8 pa0, pa1;                                                            \
    { V16 t2; t2.q = *(const u32x4*)(Pw + ((l15 * 128 + g * 16) ^ ((l15 & 7) << 4))); pa0 = t2.h; } \
    { V16 t2; t2.q = *(const u32x4*)(Pw + ((l15 * 128 + 64 + g * 16) ^ ((l15 & 7) << 4))); pa1 = t2.h; } \
    _Pragma("unroll")                                                           \
    for (int dt = 0; dt < 8; ++dt) {                                            \
      int krow = dt * 16 + l15;                                                 \
      V16 kf0; kf0.q = *(const u32x4*)((TR) + (((krow << 7) + (g << 4)) ^ ((l15 & 7) << 4))); \
      Oacc[dt] = __builtin_amdgcn_mfma_f32_16x16x32_bf16(pa0, kf0.h, Oacc[dt], 0, 0, 0); \
      V16 kf1; kf1.q = *(const u32x4*)((TR) + (((krow << 7) + 64 + (g << 4)) ^ ((l15 & 7) << 4))); \
      Oacc[dt] = __builtin_amdgcn_mfma_f32_16x16x32_bf16(pa1, kf1.h, Oacc[dt], 0, 0, 0); \
    }                                                                           \
    if (DOM) mbcur = COMPRESS();                                                \
    if (DOW) WRITELDS(KW, TW)                                                   \
    if (DOP) LOADREGS(kvbase + ((((ST) + 2 + qb) & 15) << 6))                   \
    BARRIER()                                                                   \
  }

// ---------- kernel 3: fused masked-softmax attention, QBLK=128 via 512-thread
// blocks: 8 waves share each K/Kt tile -> per-CU LDS tile traffic HALVES vs
// QBLK=64 (tile reads are identical across waves), and occupancy doubles to
// 4 waves/SIMD (LDS 80 KB = exactly 2 blocks/CU). Per-wave compute identical
// to round 12 (swapped QK^T, direct mask predication, double-buffered tiles,
// one lgkm-only barrier/step, reg-staged L2-allocating loads, diag stagger).
__launch_bounds__(512, 4)
__global__ void k_flash(const u16* __restrict__ qg, const u16* __restrict__ kg,
                        const u16* __restrict__ ktg, const int* __restrict__ M,
                        float* __restrict__ Op, float* __restrict__ lp) {
  __shared__ __align__(16) char K0[64 * 256], K1[64 * 256];   // 2x16 KB
  __shared__ __align__(16) char T0[128 * 128], T1[128 * 128]; // 2x16 KB
  __shared__ __align__(16) char Psh[8 * 2048];                // per-wave P tile
  const int tid = threadIdx.x;
  const int wid = tid >> 6, lane = tid & 63, g = lane >> 4, l15 = lane & 15;
  const int bid = blockIdx.x;
  const int split = bid & 7, qb = bid >> 3;
  const int qb0 = qb * QBLK;
  const int kvbase = split * (E_N / SPLIT);
  char* Pw = Psh + wid * 2048;
  const u32* mrow = (const u32*)M + (size_t)(qb0 + wid * 16 + l15) * E_N + 4 * g;
  u32x4 mq[4];
  u32 mbcur;

  // staging geometry, 512 threads: K row = tid>>3 (8 thr/row, segs s0,s0+8);
  // T d-row = tid>>2 (4 thr/row, segs s1,s1+4). Swizzled dests, linear global.
  const int k_row = tid >> 3, k_s = tid & 7;
  const int t_d = tid >> 2, t_s = tid & 3;
  const int kofs0 = ((k_row << 8) + (k_s << 4)) ^ ((k_row & 7) << 4);
  const int kofs1 = ((k_row << 8) + ((k_s + 8) << 4)) ^ ((k_row & 7) << 4);
  const int tofs0 = ((t_d << 7) + (t_s << 4)) ^ ((t_d & 7) << 4);
  const int tofs1 = ((t_d << 7) + ((t_s + 4) << 4)) ^ ((t_d & 7) << 4);
  const u16* kgp = kg + (size_t)k_row * 128 + k_s * 8;
  const u16* ktp = ktg + (size_t)t_d * E_N + t_s * 8;
  u32x4 kr0, kr1, tr0, tr1;

  bf16x8 qf[4];
  {
    const u16* qrow = qg + (size_t)(qb0 + wid * 16 + l15) * 128;
#pragma unroll
    for (int ks = 0; ks < 4; ++ks) {
      V16 t; t.q = *(const u32x4*)(qrow + (ks << 5) + (g << 3));
      qf[ks] = t.h;
    }
  }
  const f32x4 zero4 = {0.f, 0.f, 0.f, 0.f};
  f32x4 Oacc[8];
#pragma unroll
  for (int i = 0; i < 8; ++i) Oacc[i] = zero4;
  float lacc = 0.f;

  // prologue: chunk c0=(qb&15): tiles + masks; stage chunk c1 into regs
  {
    const int c0 = kvbase + ((qb & 15) << 6);
    MASKLOAD(c0)
    LOADREGS(c0)
    WRITELDS(K0, T0)
    mbcur = COMPRESS();
    LOADREGS(kvbase + (((qb + 1) & 15) << 6))
    BARRIER()
  }

  for (int st2 = 0; st2 < CH; st2 += 2) {
    FSTEP(st2,     K0, T0, K1, T1, true,        true,        (st2 < 14))
    FSTEP(st2 + 1, K1, T1, K0, T0, (st2 < 14),  (st2 < 14),  (st2 < 14))
  }

  // qrow sum: lane holds partial for qrow=l15; reduce across the 4 g-groups
  {
    float v = lacc;
    v += __shfl_xor(v, 16);
    v += __shfl_xor(v, 32);
    if (lane < 16)
      lp[split * E_N + qb0 + wid * 16 + lane] = v;
  }
  float* op = Op + ((size_t)split * E_N + qb0 + wid * 16) * 128;
#pragma unroll
  for (int dt = 0; dt < 8; ++dt)
#pragma unroll
    for (int r = 0; r < 4; ++r)
      op[(4 * g + r) * 128 + dt * 16 + l15] = Oacc[dt][r];
}

// ---------- kernel 4: combine KV-split partials, normalize (float4)
__global__ void k_comb(const float* __restrict__ Op, const float* __restrict__ lp,
                       float* __restrict__ out) {
  int idx4 = blockIdx.x * 256 + threadIdx.x;       // < 8192*128/4
  int base = idx4 << 2;
  int e = base >> 7;
  f32x4 o = {0.f, 0.f, 0.f, 0.f};
  float l = 0.f;
#pragma unroll
  for (int s = 0; s < SPLIT; ++s) {
    o += *(const f32x4*)(Op + (size_t)s * (E_N * 128) + base);
    l += lp[s * E_N + e];
  }
  float rl = 1.0f / l;
  o[0] *= rl; o[1] *= rl; o[2] *= rl; o[3] *= rl;
  *(f32x4*)(out + base) = o;
}

extern "C" void kernel_launch(void* const* d_in, const int* in_sizes, int n_in,
                              void* d_out, int out_size, void* d_ws, size_t ws_size,
                              hipStream_t stream) {
  const float* X  = (const float*)d_in[0];
  const float* Wq = (const float*)d_in[1];
  const float* Wk = (const float*)d_in[2];
  const int*   M  = (const int*)d_in[3];
  char* ws = (char*)d_ws;
  u16*   qg   = (u16*)(ws);                                       // 2 MB
  u16*   kg   = (u16*)(ws + (size_t)(2u << 20));                  // 2 MB
  u16*   ktg  = (u16*)(ws + (size_t)(4u << 20));                  // 2 MB
  u16*   wt   = (u16*)(ws + (size_t)(6u << 20));                  // 128 KB
  float* lp   = (float*)(ws + (size_t)(6u << 20) + (128u << 10)); // 256 KB
  float* Op   = (float*)(ws + (size_t)(6u << 20) + (512u << 10) + (8u << 20)); // 32 MB
  float* out = (float*)d_out;

  k_wt  <<<256, 256, 0, stream>>>(Wq, Wk, wt);
  k_proj<<<128, 256, 0, stream>>>(X, wt, qg, kg);
  k_kt  <<<256, 256, 0, stream>>>(kg, ktg);
  k_flash<<<SPLIT * (E_N / QBLK), 512, 0, stream>>>(qg, kg, ktg, M, Op, lp);
  k_comb<<<(E_N * 128 / 4) / 256, 256, 0, stream>>>(Op, lp, out);
}

// Round 16
// 120.596 us; speedup vs baseline: 2.6900x; 2.6900x over previous
//
#include <hip/hip_runtime.h>
#include <stdint.h>

#define E_N 8192
#define SPLIT 8
#define CH 16                 // (E_N/SPLIT)/64 kv-chunks per split
#define QBLK 64

typedef unsigned short u16;
typedef unsigned int u32;
typedef unsigned long long u64;
typedef __attribute__((ext_vector_type(4))) float f32x4;
typedef __attribute__((ext_vector_type(8))) short bf16x8;
typedef __attribute__((ext_vector_type(4))) unsigned int u32x4;
typedef __attribute__((ext_vector_type(2))) unsigned int u32x2;

union V16 { u32x4 q; bf16x8 h; u16 u[8]; };

static __device__ __forceinline__ u16 f2bf(float f) {
  union { float f; unsigned u; } c; c.f = f;
  unsigned r = c.u + 0x7FFFu + ((c.u >> 16) & 1u);
  return (u16)(r >> 16);
}

// q pre-scale folds softmax 1/sqrt(128) and log2(e) so inner loop is exp2.
constexpr float QS = 1.4426950408889634f / 11.313708498984761f;

// ---------- kernel 0: W[256][128] f32 -> Wt bf16 [2][128][256]
__global__ void k_wt(const float* __restrict__ Wq, const float* __restrict__ Wk,
                     u16* __restrict__ wt) {
  int idx = blockIdx.x * 256 + threadIdx.x;          // 0..65535
  int mat = idx >> 15, rem = idx & 32767;
  float v = mat ? Wk[rem] : Wq[rem];
  int d = rem >> 7, c = rem & 127;
  wt[(mat * 128 + c) * 256 + d] = f2bf(v);
}

// ---------- kernel 1: projections q (scaled) and k, bf16 [8192][128]
__launch_bounds__(256)
__global__ void k_proj(const float* __restrict__ X, const u16* __restrict__ wt,
                       u16* __restrict__ qg, u16* __restrict__ kg) {
  __shared__ __align__(16) char Xs[64 * 512];        // bf16 [64][256], xor-swizzled
  const int tid = threadIdx.x;
  const int wid = tid >> 6, lane = tid & 63, g = lane >> 4, l15 = lane & 15;
  const int r0 = blockIdx.x * 64;
#pragma unroll
  for (int i = 0; i < 16; ++i) {
    int s = tid + 256 * i;                           // 0..4095 float4 tasks
    int row = s >> 6, c4 = (s & 63) << 2;
    f32x4 v = *(const f32x4*)(X + (size_t)(r0 + row) * 256 + c4);
    u32x2 pk;
    pk[0] = f2bf(v[0]) | ((unsigned)f2bf(v[1]) << 16);
    pk[1] = f2bf(v[2]) | ((unsigned)f2bf(v[3]) << 16);
    *(u32x2*)(Xs + (((row << 9) + (c4 << 1)) ^ ((row & 7) << 4))) = pk;
  }
  __syncthreads();
  bf16x8 xa[8];
  const int arow = wid * 16 + l15;
#pragma unroll
  for (int ks = 0; ks < 8; ++ks) {
    V16 t; t.q = *(const u32x4*)(Xs + (((arow << 9) + (ks << 6) + (g << 4)) ^ ((l15 & 7) << 4)));
    xa[ks] = t.h;
  }
  const f32x4 zero4 = {0.f, 0.f, 0.f, 0.f};
  f32x4 acc[16];
#pragma unroll
  for (int i = 0; i < 16; ++i) acc[i] = zero4;
#pragma unroll
  for (int ct = 0; ct < 16; ++ct) {
    int mat = ct >> 3, c = ((ct & 7) << 4) + l15;
#pragma unroll
    for (int ks = 0; ks < 8; ++ks) {
      V16 b; b.q = *(const u32x4*)(wt + ((mat * 128 + c) * 256 + (ks << 5) + (g << 3)));
      acc[ct] = __builtin_amdgcn_mfma_f32_16x16x32_bf16(xa[ks], b.h, acc[ct], 0, 0, 0);
    }
  }
#pragma unroll
  for (int ct = 0; ct < 16; ++ct) {
    int mat = ct >> 3, c = ((ct & 7) << 4) + l15;
#pragma unroll
    for (int r = 0; r < 4; ++r) {
      int row = r0 + wid * 16 + 4 * g + r;
      float v = acc[ct][r];
      if (mat == 0) qg[row * 128 + c] = f2bf(v * QS);
      else          kg[row * 128 + c] = f2bf(v);
    }
  }
}

// ---------- kernel 2: kt[128][8192] = k^T (bf16), LDS-tiled transpose
__global__ void k_kt(const u16* __restrict__ kg, u16* __restrict__ ktg) {
  __shared__ __align__(16) u16 Ts[64 * 66];          // pitch 66 (132 B) for bank spread
  const int tid = threadIdx.x;
  const int b = blockIdx.x;
  const int r0 = (b >> 1) * 64, c0 = (b & 1) * 64;
#pragma unroll
  for (int i = 0; i < 2; ++i) {
    int s = tid + 256 * i;                           // 0..511
    int row = s >> 3, seg = s & 7;
    u32x4 v = *(const u32x4*)(kg + (size_t)(r0 + row) * 128 + c0 + seg * 8);
    unsigned* dst = (unsigned*)((char*)Ts + row * 132 + seg * 16);
    dst[0] = v[0]; dst[1] = v[1]; dst[2] = v[2]; dst[3] = v[3];
  }
  __syncthreads();
#pragma unroll
  for (int i = 0; i < 2; ++i) {
    int s = tid + 256 * i;
    int oc = s >> 3, seg2 = s & 7;
    u16 t[8];
#pragma unroll
    for (int j = 0; j < 8; ++j) t[j] = Ts[(seg2 * 8 + j) * 66 + oc];
    u32x4 o;
    o[0] = t[0] | ((unsigned)t[1] << 16);
    o[1] = t[2] | ((unsigned)t[3] << 16);
    o[2] = t[4] | ((unsigned)t[5] << 16);
    o[3] = t[6] | ((unsigned)t[7] << 16);
    *(u32x4*)(ktg + (size_t)(c0 + oc) * E_N + r0 + seg2 * 8) = o;
  }
}

// lgkm-only barrier: raw s_barrier WITHOUT the vmcnt(0) drain (T3/T4) ->
// global loads stay in flight across step boundaries.
#define BARRIER() { asm volatile("s_waitcnt lgkmcnt(0)" ::: "memory"); \
                    __builtin_amdgcn_s_barrier(); }

// Reg-staged tile load: 8 x global dwordx4 into named regs (L2-allocating,
// unlike global_load_lds whose fetches got 0% L2 hit across rounds 2-7).
#define LOADREGS(KV1)                                                           \
  {                                                                             \
    const u16* kp = kgp + (size_t)(KV1) * 128;                                  \
    kr0 = *(const u32x4*)(kp);                                                  \
    kr1 = *(const u32x4*)(kp + 16 * 128);                                       \
    kr2 = *(const u32x4*)(kp + 32 * 128);                                       \
    kr3 = *(const u32x4*)(kp + 48 * 128);                                       \
    const u16* tp = ktp + (KV1);                                                \
    tr0 = *(const u32x4*)(tp);                                                  \
    tr1 = *(const u32x4*)(tp + 32 * E_N);                                       \
    tr2 = *(const u32x4*)(tp + 64 * E_N);                                       \
    tr3 = *(const u32x4*)(tp + 96 * E_N);                                       \
  }

#define WRITELDS(KW, TW)                                                        \
  {                                                                             \
    *(u32x4*)((KW) + kofs)          = kr0;                                      \
    *(u32x4*)((KW) + kofs + 4096)   = kr1;                                      \
    *(u32x4*)((KW) + kofs + 8192)   = kr2;                                      \
    *(u32x4*)((KW) + kofs + 12288)  = kr3;                                      \
    *(u32x4*)((TW) + tofs)          = tr0;                                      \
    *(u32x4*)((TW) + tofs + 4096)   = tr1;                                      \
    *(u32x4*)((TW) + tofs + 8192)   = tr2;                                      \
    *(u32x4*)((TW) + tofs + 12288)  = tr3;                                      \
  }

// Swapped-QK^T mask path: S^T = mfma(K,Q) puts qrow in col=lane&15, kv in
// row=4g+r -> lane's mask for tile t is M[qrow][kv0+16t+4g..+3]: ONE aligned
// dwordx4, consumed directly. Two chunks loaded back-to-back (512B/row).
#define MASKLOAD(SET, KV1)                                                      \
  {                                                                             \
    _Pragma("unroll")                                                           \
    for (int t4 = 0; t4 < 4; ++t4)                                              \
      SET[t4] = *(const u32x4*)(mrow + (KV1) + t4 * 16);                        \
  }

// One flash step, ONE barrier. QK^T (swapped, setprio-wrapped) -> masked exp2
// -> packed-b64 P write -> [mask burst after mqb's last use] -> pa read ->
// PV (setprio-wrapped) -> tile write (chunk st+1, regs from prev step) ->
// tile load (chunk st+2) -> lgkm-barrier.
#define FSTEP(SUB, KR, TR, KW, TW, MSET, DOM, DOP, DOW)                         \
  {                                                                             \
    f32x4 S[4];                                                                 \
    _Pragma("unroll")                                                           \
    for (int t = 0; t < 4; ++t) S[t] = zero4;                                   \
    __builtin_amdgcn_s_setprio(1);                                              \
    _Pragma("unroll")                                                           \
    for (int t = 0; t < 4; ++t) {                                               \
      int krow = t * 16 + l15;                                                  \
      _Pragma("unroll")                                                         \
      for (int ks = 0; ks < 4; ++ks) {                                          \
        V16 kf; kf.q = *(const u32x4*)((KR) + (((krow << 8) + (ks << 6) + (g << 4)) ^ ((l15 & 7) << 4))); \
        S[t] = __builtin_amdgcn_mfma_f32_16x16x32_bf16(kf.h, qf[ks], S[t], 0, 0, 0); \
      }                                                                         \
    }                                                                           \
    __builtin_amdgcn_s_setprio(0);                                              \
    _Pragma("unroll")                                                           \
    for (int t = 0; t < 4; ++t) {                                               \
      float p0 = MSET[t][0] ? __builtin_amdgcn_exp2f(S[t][0]) : 0.f;            \
      float p1 = MSET[t][1] ? __builtin_amdgcn_exp2f(S[t][1]) : 0.f;            \
      float p2 = MSET[t][2] ? __builtin_amdgcn_exp2f(S[t][2]) : 0.f;            \
      float p3 = MSET[t][3] ? __builtin_amdgcn_exp2f(S[t][3]) : 0.f;            \
      lacc += (p0 + p1) + (p2 + p3);                                            \
      u32x2 pk;                                                                 \
      pk[0] = f2bf(p0) | ((u32)f2bf(p1) << 16);                                 \
      pk[1] = f2bf(p2) | ((u32)f2bf(p3) << 16);                                 \
      *(u32x2*)(Pw + ((l15 * 128 + (t * 16 + 4 * g) * 2) ^ ((l15 & 7) << 4))) = pk; \
    }                                                                           \
    if (DOM) {                                                                  \
      MASKLOAD(mqa, kvbase + (((st2 + 2 + qb) & 15) << 6))                      \
      MASKLOAD(mqb, kvbase + (((st2 + 3 + qb) & 15) << 6))                      \
    }                                                                           \
    bf16x8 pa0, pa1;                                                            \
    { V16 t2; t2.q = *(const u32x4*)(Pw + ((l15 * 128 + g * 16) ^ ((l15 & 7) << 4))); pa0 = t2.h; } \
    { V16 t2; t2.q = *(const u32x4*)(Pw + ((l15 * 128 + 64 + g * 16) ^ ((l15 & 7) << 4))); pa1 = t2.h; } \
    __builtin_amdgcn_s_setprio(1);                                              \
    _Pragma("unroll")                                                           \
    for (int dt = 0; dt < 8; ++dt) {                                            \
      int krow = dt * 16 + l15;                                                 \
      V16 kf0; kf0.q = *(const u32x4*)((TR) + (((krow << 7) + (g << 4)) ^ ((l15 & 7) << 4))); \
      Oacc[dt] = __builtin_amdgcn_mfma_f32_16x16x32_bf16(pa0, kf0.h, Oacc[dt], 0, 0, 0); \
      V16 kf1; kf1.q = *(const u32x4*)((TR) + (((krow << 7) + 64 + (g << 4)) ^ ((l15 & 7) << 4))); \
      Oacc[dt] = __builtin_amdgcn_mfma_f32_16x16x32_bf16(pa1, kf1.h, Oacc[dt], 0, 0, 0); \
    }                                                                           \
    __builtin_amdgcn_s_setprio(0);                                              \
    if (DOW) WRITELDS(KW, TW)                                                   \
    if (DOP) {                                                                  \
      const int kvt = kvbase + (((st2 + (SUB) + 2 + qb) & 15) << 6);            \
      LOADREGS(kvt)                                                             \
    }                                                                           \
    if (DOW) BARRIER()                                                          \
  }

// ---------- kernel 3: fused masked-softmax attention (round-12 structure:
// reg-staged double-buffered tiles, swapped-operand QK^T with direct dwordx4
// mask predication, lgkm-only barriers, 2-chunk mask bursts, diag stagger)
// + T5 s_setprio around the MFMA clusters. grid 1024: split=bid&7, qb=bid>>3.
__launch_bounds__(256, 2)
__global__ void k_flash(const u16* __restrict__ qg, const u16* __restrict__ kg,
                        const u16* __restrict__ ktg, const int* __restrict__ M,
                        float* __restrict__ Op, float* __restrict__ lp) {
  __shared__ __align__(16) char K0[64 * 256], K1[64 * 256];   // 2x16 KB
  __shared__ __align__(16) char T0[128 * 128], T1[128 * 128]; // 2x16 KB
  __shared__ __align__(16) char Psh[4 * 2048];                // per-wave P tile
  const int tid = threadIdx.x;
  const int wid = tid >> 6, lane = tid & 63, g = lane >> 4, l15 = lane & 15;
  const int bid = blockIdx.x;
  const int split = bid & 7, qb = bid >> 3;
  const int qb0 = qb * QBLK;
  const int kvbase = split * (E_N / SPLIT);
  char* Pw = Psh + wid * 2048;
  const u32* mrow = (const u32*)M + (size_t)(qb0 + wid * 16 + l15) * E_N + 4 * g;
  u32x4 mqa[4], mqb[4];

  // staging lane geometry (swizzled LDS dest, linear global source)
  const int kr_r = tid >> 4, kr_s = tid & 15;   // K: rows kr_r+16i, 16B seg kr_s
  const int tr_d = tid >> 3, tr_s = tid & 7;    // Kt: d tr_d+32i, 16B seg tr_s
  const int kofs = ((kr_r << 8) + (kr_s << 4)) ^ ((kr_r & 7) << 4);
  const int tofs = ((tr_d << 7) + (tr_s << 4)) ^ ((tr_d & 7) << 4);
  const u16* kgp = kg + (size_t)kr_r * 128 + kr_s * 8;
  const u16* ktp = ktg + (size_t)tr_d * E_N + tr_s * 8;
  u32x4 kr0, kr1, kr2, kr3, tr0, tr1, tr2, tr3;

  bf16x8 qf[4];
  {
    const u16* qrow = qg + (size_t)(qb0 + wid * 16 + l15) * 128;
#pragma unroll
    for (int ks = 0; ks < 4; ++ks) {
      V16 t; t.q = *(const u32x4*)(qrow + (ks << 5) + (g << 3));
      qf[ks] = t.h;
    }
  }
  const f32x4 zero4 = {0.f, 0.f, 0.f, 0.f};
  f32x4 Oacc[8];
#pragma unroll
  for (int i = 0; i < 8; ++i) Oacc[i] = zero4;
  float lacc = 0.f;

  // prologue: chunks c0=(qb&15), c1=(qb+1)&15 (mask burst + tiles c0, c1)
  {
    const int c0 = (qb & 15) << 6;
    const int c1 = ((qb + 1) & 15) << 6;
    MASKLOAD(mqa, kvbase + c0)
    MASKLOAD(mqb, kvbase + c1)
    LOADREGS(kvbase + c0)
    WRITELDS(K0, T0)
    LOADREGS(kvbase + c1)
    BARRIER()
  }

  for (int st2 = 0; st2 < CH; st2 += 2) {
    FSTEP(0, K0, T0, K1, T1, mqa, false, (st2 < 14), true)
    FSTEP(1, K1, T1, K0, T0, mqb, (st2 < 14), (st2 < 14), (st2 < 14))
  }

  // qrow sum: lane holds partial for qrow=l15; reduce across the 4 g-groups
  {
    float v = lacc;
    v += __shfl_xor(v, 16);
    v += __shfl_xor(v, 32);
    if (lane < 16)
      lp[split * E_N + qb0 + wid * 16 + lane] = v;
  }
  float* op = Op + ((size_t)split * E_N + qb0 + wid * 16) * 128;
#pragma unroll
  for (int dt = 0; dt < 8; ++dt)
#pragma unroll
    for (int r = 0; r < 4; ++r)
      op[(4 * g + r) * 128 + dt * 16 + l15] = Oacc[dt][r];
}

// ---------- kernel 4: combine KV-split partials, normalize (float4)
__global__ void k_comb(const float* __restrict__ Op, const float* __restrict__ lp,
                       float* __restrict__ out) {
  int idx4 = blockIdx.x * 256 + threadIdx.x;       // < 8192*128/4
  int base = idx4 << 2;
  int e = base >> 7;
  f32x4 o = {0.f, 0.f, 0.f, 0.f};
  float l = 0.f;
#pragma unroll
  for (int s = 0; s < SPLIT; ++s) {
    o += *(const f32x4*)(Op + (size_t)s * (E_N * 128) + base);
    l += lp[s * E_N + e];
  }
  float rl = 1.0f / l;
  o[0] *= rl; o[1] *= rl; o[2] *= rl; o[3] *= rl;
  *(f32x4*)(out + base) = o;
}

extern "C" void kernel_launch(void* const* d_in, const int* in_sizes, int n_in,
                              void* d_out, int out_size, void* d_ws, size_t ws_size,
                              hipStream_t stream) {
  const float* X  = (const float*)d_in[0];
  const float* Wq = (const float*)d_in[1];
  const float* Wk = (const float*)d_in[2];
  const int*   M  = (const int*)d_in[3];
  char* ws = (char*)d_ws;
  u16*   qg   = (u16*)(ws);                                       // 2 MB
  u16*   kg   = (u16*)(ws + (size_t)(2u << 20));                  // 2 MB
  u16*   ktg  = (u16*)(ws + (size_t)(4u << 20));                  // 2 MB
  u16*   wt   = (u16*)(ws + (size_t)(6u << 20));                  // 128 KB
  float* lp   = (float*)(ws + (size_t)(6u << 20) + (128u << 10)); // 256 KB
  float* Op   = (float*)(ws + (size_t)(6u << 20) + (512u << 10) + (8u << 20)); // 32 MB
  float* out = (float*)d_out;

  k_wt  <<<256, 256, 0, stream>>>(Wq, Wk, wt);
  k_proj<<<128, 256, 0, stream>>>(X, wt, qg, kg);
  k_kt  <<<256, 256, 0, stream>>>(kg, ktg);
  k_flash<<<SPLIT * (E_N / QBLK), 256, 0, stream>>>(qg, kg, ktg, M, Op, lp);
  k_comb<<<(E_N * 128 / 4) / 256, 256, 0, stream>>>(Op, lp, out);
}

// Round 18
// 115.522 us; speedup vs baseline: 2.8081x; 1.0439x over previous
//
#include <hip/hip_runtime.h>
#include <stdint.h>

#define E_N 8192
#define SPLIT 4
#define CH 32                 // (E_N/SPLIT)/64 kv-chunks per split
#define QBLK 64

typedef unsigned short u16;
typedef unsigned int u32;
typedef unsigned long long u64;
typedef __attribute__((ext_vector_type(4))) float f32x4;
typedef __attribute__((ext_vector_type(8))) short bf16x8;
typedef __attribute__((ext_vector_type(4))) unsigned int u32x4;
typedef __attribute__((ext_vector_type(2))) unsigned int u32x2;

union V16 { u32x4 q; bf16x8 h; u16 u[8]; };

static __device__ __forceinline__ u16 f2bf(float f) {
  union { float f; unsigned u; } c; c.f = f;
  unsigned r = c.u + 0x7FFFu + ((c.u >> 16) & 1u);
  return (u16)(r >> 16);
}

// q pre-scale folds softmax 1/sqrt(128) and log2(e) so inner loop is exp2.
constexpr float QS = 1.4426950408889634f / 11.313708498984761f;

// ---------- kernel 0: W[256][128] f32 -> Wt bf16 [2][128][256]
__global__ void k_wt(const float* __restrict__ Wq, const float* __restrict__ Wk,
                     u16* __restrict__ wt) {
  int idx = blockIdx.x * 256 + threadIdx.x;          // 0..65535
  int mat = idx >> 15, rem = idx & 32767;
  float v = mat ? Wk[rem] : Wq[rem];
  int d = rem >> 7, c = rem & 127;
  wt[(mat * 128 + c) * 256 + d] = f2bf(v);
}

// ---------- kernel 1: projections q (scaled) and k, bf16 [8192][128]
__launch_bounds__(256)
__global__ void k_proj(const float* __restrict__ X, const u16* __restrict__ wt,
                       u16* __restrict__ qg, u16* __restrict__ kg) {
  __shared__ __align__(16) char Xs[64 * 512];        // bf16 [64][256], xor-swizzled
  const int tid = threadIdx.x;
  const int wid = tid >> 6, lane = tid & 63, g = lane >> 4, l15 = lane & 15;
  const int r0 = blockIdx.x * 64;
#pragma unroll
  for (int i = 0; i < 16; ++i) {
    int s = tid + 256 * i;                           // 0..4095 float4 tasks
    int row = s >> 6, c4 = (s & 63) << 2;
    f32x4 v = *(const f32x4*)(X + (size_t)(r0 + row) * 256 + c4);
    u32x2 pk;
    pk[0] = f2bf(v[0]) | ((unsigned)f2bf(v[1]) << 16);
    pk[1] = f2bf(v[2]) | ((unsigned)f2bf(v[3]) << 16);
    *(u32x2*)(Xs + (((row << 9) + (c4 << 1)) ^ ((row & 7) << 4))) = pk;
  }
  __syncthreads();
  bf16x8 xa[8];
  const int arow = wid * 16 + l15;
#pragma unroll
  for (int ks = 0; ks < 8; ++ks) {
    V16 t; t.q = *(const u32x4*)(Xs + (((arow << 9) + (ks << 6) + (g << 4)) ^ ((l15 & 7) << 4)));
    xa[ks] = t.h;
  }
  const f32x4 zero4 = {0.f, 0.f, 0.f, 0.f};
  f32x4 acc[16];
#pragma unroll
  for (int i = 0; i < 16; ++i) acc[i] = zero4;
#pragma unroll
  for (int ct = 0; ct < 16; ++ct) {
    int mat = ct >> 3, c = ((ct & 7) << 4) + l15;
#pragma unroll
    for (int ks = 0; ks < 8; ++ks) {
      V16 b; b.q = *(const u32x4*)(wt + ((mat * 128 + c) * 256 + (ks << 5) + (g << 3)));
      acc[ct] = __builtin_amdgcn_mfma_f32_16x16x32_bf16(xa[ks], b.h, acc[ct], 0, 0, 0);
    }
  }
#pragma unroll
  for (int ct = 0; ct < 16; ++ct) {
    int mat = ct >> 3, c = ((ct & 7) << 4) + l15;
#pragma unroll
    for (int r = 0; r < 4; ++r) {
      int row = r0 + wid * 16 + 4 * g + r;
      float v = acc[ct][r];
      if (mat == 0) qg[row * 128 + c] = f2bf(v * QS);
      else          kg[row * 128 + c] = f2bf(v);
    }
  }
}

// ---------- kernel 2: kt[128][8192] = k^T (bf16), LDS-tiled transpose
__global__ void k_kt(const u16* __restrict__ kg, u16* __restrict__ ktg) {
  __shared__ __align__(16) u16 Ts[64 * 66];          // pitch 66 (132 B) for bank spread
  const int tid = threadIdx.x;
  const int b = blockIdx.x;
  const int r0 = (b >> 1) * 64, c0 = (b & 1) * 64;
#pragma unroll
  for (int i = 0; i < 2; ++i) {
    int s = tid + 256 * i;                           // 0..511
    int row = s >> 3, seg = s & 7;
    u32x4 v = *(const u32x4*)(kg + (size_t)(r0 + row) * 128 + c0 + seg * 8);
    unsigned* dst = (unsigned*)((char*)Ts + row * 132 + seg * 16);
    dst[0] = v[0]; dst[1] = v[1]; dst[2] = v[2]; dst[3] = v[3];
  }
  __syncthreads();
#pragma unroll
  for (int i = 0; i < 2; ++i) {
    int s = tid + 256 * i;
    int oc = s >> 3, seg2 = s & 7;
    u16 t[8];
#pragma unroll
    for (int j = 0; j < 8; ++j) t[j] = Ts[(seg2 * 8 + j) * 66 + oc];
    u32x4 o;
    o[0] = t[0] | ((unsigned)t[1] << 16);
    o[1] = t[2] | ((unsigned)t[3] << 16);
    o[2] = t[4] | ((unsigned)t[5] << 16);
    o[3] = t[6] | ((unsigned)t[7] << 16);
    *(u32x4*)(ktg + (size_t)(c0 + oc) * E_N + r0 + seg2 * 8) = o;
  }
}

// lgkm-only barrier: raw s_barrier WITHOUT the vmcnt(0) drain (T3/T4) ->
// global loads stay in flight across step boundaries.
#define BARRIER() { asm volatile("s_waitcnt lgkmcnt(0)" ::: "memory"); \
                    __builtin_amdgcn_s_barrier(); }

// Reg-staged tile load: 8 x global dwordx4 into named regs (L2-allocating,
// unlike global_load_lds whose fetches got 0% L2 hit across rounds 2-7).
#define LOADREGS(KV1)                                                           \
  {                                                                             \
    const u16* kp = kgp + (size_t)(KV1) * 128;                                  \
    kr0 = *(const u32x4*)(kp);                                                  \
    kr1 = *(const u32x4*)(kp + 16 * 128);                                       \
    kr2 = *(const u32x4*)(kp + 32 * 128);                                       \
    kr3 = *(const u32x4*)(kp + 48 * 128);                                       \
    const u16* tp = ktp + (KV1);                                                \
    tr0 = *(const u32x4*)(tp);                                                  \
    tr1 = *(const u32x4*)(tp + 32 * E_N);                                       \
    tr2 = *(const u32x4*)(tp + 64 * E_N);                                       \
    tr3 = *(const u32x4*)(tp + 96 * E_N);                                       \
  }

#define WRITELDS(KW, TW)                                                        \
  {                                                                             \
    *(u32x4*)((KW) + kofs)          = kr0;                                      \
    *(u32x4*)((KW) + kofs + 4096)   = kr1;                                      \
    *(u32x4*)((KW) + kofs + 8192)   = kr2;                                      \
    *(u32x4*)((KW) + kofs + 12288)  = kr3;                                      \
    *(u32x4*)((TW) + tofs)          = tr0;                                      \
    *(u32x4*)((TW) + tofs + 4096)   = tr1;                                      \
    *(u32x4*)((TW) + tofs + 8192)   = tr2;                                      \
    *(u32x4*)((TW) + tofs + 12288)  = tr3;                                      \
  }

// Swapped-QK^T mask path: S^T = mfma(K,Q) puts qrow in col=lane&15, kv in
// row=4g+r -> lane's mask for tile t is M[qrow][kv0+16t+4g..+3]: ONE aligned
// dwordx4, consumed directly. Two chunks loaded back-to-back (512B/row).
#define MASKLOAD(SET, KV1)                                                      \
  {                                                                             \
    _Pragma("unroll")                                                           \
    for (int t4 = 0; t4 < 4; ++t4)                                              \
      SET[t4] = *(const u32x4*)(mrow + (KV1) + t4 * 16);                        \
  }

// One flash step, ONE barrier. QK^T (swapped, setprio-wrapped) -> masked exp2
// -> packed-b64 P write -> [mask burst after mqb's last use] -> pa read ->
// PV (setprio-wrapped) -> tile write (chunk st+1, regs from prev step) ->
// tile load (chunk st+2) -> lgkm-barrier.
#define FSTEP(SUB, KR, TR, KW, TW, MSET, DOM, DOP, DOW)                         \
  {                                                                             \
    f32x4 S[4];                                                                 \
    _Pragma("unroll")                                                           \
    for (int t = 0; t < 4; ++t) S[t] = zero4;                                   \
    __builtin_amdgcn_s_setprio(1);                                              \
    _Pragma("unroll")                                                           \
    for (int t = 0; t < 4; ++t) {                                               \
      int krow = t * 16 + l15;                                                  \
      _Pragma("unroll")                                                         \
      for (int ks = 0; ks < 4; ++ks) {                                          \
        V16 kf; kf.q = *(const u32x4*)((KR) + (((krow << 8) + (ks << 6) + (g << 4)) ^ ((l15 & 7) << 4))); \
        S[t] = __builtin_amdgcn_mfma_f32_16x16x32_bf16(kf.h, qf[ks], S[t], 0, 0, 0); \
      }                                                                         \
    }                                                                           \
    __builtin_amdgcn_s_setprio(0);                                              \
    _Pragma("unroll")                                                           \
    for (int t = 0; t < 4; ++t) {                                               \
      float p0 = MSET[t][0] ? __builtin_amdgcn_exp2f(S[t][0]) : 0.f;            \
      float p1 = MSET[t][1] ? __builtin_amdgcn_exp2f(S[t][1]) : 0.f;            \
      float p2 = MSET[t][2] ? __builtin_amdgcn_exp2f(S[t][2]) : 0.f;            \
      float p3 = MSET[t][3] ? __builtin_amdgcn_exp2f(S[t][3]) : 0.f;            \
      lacc += (p0 + p1) + (p2 + p3);                                            \
      u32x2 pk;                                                                 \
      pk[0] = f2bf(p0) | ((u32)f2bf(p1) << 16);                                 \
      pk[1] = f2bf(p2) | ((u32)f2bf(p3) << 16);                                 \
      *(u32x2*)(Pw + ((l15 * 128 + (t * 16 + 4 * g) * 2) ^ ((l15 & 7) << 4))) = pk; \
    }                                                                           \
    if (DOM) {                                                                  \
      MASKLOAD(mqa, kvbase + (((st2 + 2 + qb) & (CH - 1)) << 6))                \
      MASKLOAD(mqb, kvbase + (((st2 + 3 + qb) & (CH - 1)) << 6))                \
    }                                                                           \
    bf16x8 pa0, pa1;                                                            \
    { V16 t2; t2.q = *(const u32x4*)(Pw + ((l15 * 128 + g * 16) ^ ((l15 & 7) << 4))); pa0 = t2.h; } \
    { V16 t2; t2.q = *(const u32x4*)(Pw + ((l15 * 128 + 64 + g * 16) ^ ((l15 & 7) << 4))); pa1 = t2.h; } \
    __builtin_amdgcn_s_setprio(1);                                              \
    _Pragma("unroll")                                                           \
    for (int dt = 0; dt < 8; ++dt) {                                            \
      int krow = dt * 16 + l15;                                                 \
      V16 kf0; kf0.q = *(const u32x4*)((TR) + (((krow << 7) + (g << 4)) ^ ((l15 & 7) << 4))); \
      Oacc[dt] = __builtin_amdgcn_mfma_f32_16x16x32_bf16(pa0, kf0.h, Oacc[dt], 0, 0, 0); \
      V16 kf1; kf1.q = *(const u32x4*)((TR) + (((krow << 7) + 64 + (g << 4)) ^ ((l15 & 7) << 4))); \
      Oacc[dt] = __builtin_amdgcn_mfma_f32_16x16x32_bf16(pa1, kf1.h, Oacc[dt], 0, 0, 0); \
    }                                                                           \
    __builtin_amdgcn_s_setprio(0);                                              \
    if (DOW) WRITELDS(KW, TW)                                                   \
    if (DOP) {                                                                  \
      const int kvt = kvbase + (((st2 + (SUB) + 2 + qb) & (CH - 1)) << 6);      \
      LOADREGS(kvt)                                                             \
    }                                                                           \
    if (DOW) BARRIER()                                                          \
  }

// ---------- kernel 3: fused masked-softmax attention (round-16 structure:
// reg-staged double-buffered tiles, swapped-operand QK^T with direct dwordx4
// mask predication, lgkm-only barriers, 2-chunk mask bursts, diag stagger,
// setprio). SPLIT=4 -> grid 512 = exactly 2 blocks/CU, single generation,
// fully resident; Op/lp combine traffic halved. split=bid&3, qb=bid>>2.
__launch_bounds__(256, 2)
__global__ void k_flash(const u16* __restrict__ qg, const u16* __restrict__ kg,
                        const u16* __restrict__ ktg, const int* __restrict__ M,
                        float* __restrict__ Op, float* __restrict__ lp) {
  __shared__ __align__(16) char K0[64 * 256], K1[64 * 256];   // 2x16 KB
  __shared__ __align__(16) char T0[128 * 128], T1[128 * 128]; // 2x16 KB
  __shared__ __align__(16) char Psh[4 * 2048];                // per-wave P tile
  const int tid = threadIdx.x;
  const int wid = tid >> 6, lane = tid & 63, g = lane >> 4, l15 = lane & 15;
  const int bid = blockIdx.x;
  const int split = bid & (SPLIT - 1), qb = bid >> 2;
  const int qb0 = qb * QBLK;
  const int kvbase = split * (E_N / SPLIT);
  char* Pw = Psh + wid * 2048;
  const u32* mrow = (const u32*)M + (size_t)(qb0 + wid * 16 + l15) * E_N + 4 * g;
  u32x4 mqa[4], mqb[4];

  // staging lane geometry (swizzled LDS dest, linear global source)
  const int kr_r = tid >> 4, kr_s = tid & 15;   // K: rows kr_r+16i, 16B seg kr_s
  const int tr_d = tid >> 3, tr_s = tid & 7;    // Kt: d tr_d+32i, 16B seg tr_s
  const int kofs = ((kr_r << 8) + (kr_s << 4)) ^ ((kr_r & 7) << 4);
  const int tofs = ((tr_d << 7) + (tr_s << 4)) ^ ((tr_d & 7) << 4);
  const u16* kgp = kg + (size_t)kr_r * 128 + kr_s * 8;
  const u16* ktp = ktg + (size_t)tr_d * E_N + tr_s * 8;
  u32x4 kr0, kr1, kr2, kr3, tr0, tr1, tr2, tr3;

  bf16x8 qf[4];
  {
    const u16* qrow = qg + (size_t)(qb0 + wid * 16 + l15) * 128;
#pragma unroll
    for (int ks = 0; ks < 4; ++ks) {
      V16 t; t.q = *(const u32x4*)(qrow + (ks << 5) + (g << 3));
      qf[ks] = t.h;
    }
  }
  const f32x4 zero4 = {0.f, 0.f, 0.f, 0.f};
  f32x4 Oacc[8];
#pragma unroll
  for (int i = 0; i < 8; ++i) Oacc[i] = zero4;
  float lacc = 0.f;

  // prologue: chunks c0=(qb&31), c1=(qb+1)&31 (mask burst + tiles c0, c1)
  {
    const int c0 = (qb & (CH - 1)) << 6;
    const int c1 = ((qb + 1) & (CH - 1)) << 6;
    MASKLOAD(mqa, kvbase + c0)
    MASKLOAD(mqb, kvbase + c1)
    LOADREGS(kvbase + c0)
    WRITELDS(K0, T0)
    LOADREGS(kvbase + c1)
    BARRIER()
  }

  for (int st2 = 0; st2 < CH; st2 += 2) {
    FSTEP(0, K0, T0, K1, T1, mqa, false, (st2 < CH - 2), true)
    FSTEP(1, K1, T1, K0, T0, mqb, (st2 < CH - 2), (st2 < CH - 2), (st2 < CH - 2))
  }

  // qrow sum: lane holds partial for qrow=l15; reduce across the 4 g-groups
  {
    float v = lacc;
    v += __shfl_xor(v, 16);
    v += __shfl_xor(v, 32);
    if (lane < 16)
      lp[split * E_N + qb0 + wid * 16 + lane] = v;
  }
  float* op = Op + ((size_t)split * E_N + qb0 + wid * 16) * 128;
#pragma unroll
  for (int dt = 0; dt < 8; ++dt)
#pragma unroll
    for (int r = 0; r < 4; ++r)
      op[(4 * g + r) * 128 + dt * 16 + l15] = Oacc[dt][r];
}

// ---------- kernel 4: combine KV-split partials, normalize (float4)
__global__ void k_comb(const float* __restrict__ Op, const float* __restrict__ lp,
                       float* __restrict__ out) {
  int idx4 = blockIdx.x * 256 + threadIdx.x;       // < 8192*128/4
  int base = idx4 << 2;
  int e = base >> 7;
  f32x4 o = {0.f, 0.f, 0.f, 0.f};
  float l = 0.f;
#pragma unroll
  for (int s = 0; s < SPLIT; ++s) {
    o += *(const f32x4*)(Op + (size_t)s * (E_N * 128) + base);
    l += lp[s * E_N + e];
  }
  float rl = 1.0f / l;
  o[0] *= rl; o[1] *= rl; o[2] *= rl; o[3] *= rl;
  *(f32x4*)(out + base) = o;
}

extern "C" void kernel_launch(void* const* d_in, const int* in_sizes, int n_in,
                              void* d_out, int out_size, void* d_ws, size_t ws_size,
                              hipStream_t stream) {
  const float* X  = (const float*)d_in[0];
  const float* Wq = (const float*)d_in[1];
  const float* Wk = (const float*)d_in[2];
  const int*   M  = (const int*)d_in[3];
  char* ws = (char*)d_ws;
  u16*   qg   = (u16*)(ws);                                       // 2 MB
  u16*   kg   = (u16*)(ws + (size_t)(2u << 20));                  // 2 MB
  u16*   ktg  = (u16*)(ws + (size_t)(4u << 20));                  // 2 MB
  u16*   wt   = (u16*)(ws + (size_t)(6u << 20));                  // 128 KB
  float* lp   = (float*)(ws + (size_t)(6u << 20) + (128u << 10)); // 256 KB
  float* Op   = (float*)(ws + (size_t)(6u << 20) + (512u << 10) + (8u << 20)); // 16 MB
  float* out = (float*)d_out;

  k_wt  <<<256, 256, 0, stream>>>(Wq, Wk, wt);
  k_proj<<<128, 256, 0, stream>>>(X, wt, qg, kg);
  k_kt  <<<256, 256, 0, stream>>>(kg, ktg);
  k_flash<<<SPLIT * (E_N / QBLK), 256, 0, stream>>>(qg, kg, ktg, M, Op, lp);
  k_comb<<<(E_N * 128 / 4) / 256, 256, 0, stream>>>(Op, lp, out);
}